// Round 22
// baseline (60.040 us; speedup 1.0000x reference)
//
#include <hip/hip_runtime.h>
#include <hip/hip_bf16.h>

typedef __attribute__((ext_vector_type(4)))  int   i32x4;
typedef __attribute__((ext_vector_type(16))) int   i32x16;

#define DIM_D 256
#define DIM_O 256
#define DIM_K 8
#define BM 128
#define NCHUNK 16                 // 16 chunks of 16 d-values
#define NSTEP 4                   // 4 K=32 steps per chunk (4 d's each)
#define MAGIC 12582912.f          // 1.5 * 2^23 : fma+byte-extract = rint to int8

// ---- pack kernel: one block per output row o (verified r12-r21) ----
// Per-o scale s_o = max|c[o,:,:]|, quantize into 32x32x32 i8 MFMA B-frag order:
// byte addr = ((s*8 + ct)*64 + lane)*16 + j, where for (o,d,k):
//   s = d>>2, ct = o>>5, lane = ((d>>1)&1)*32 + (o&31), j = (d&1)*8 + k
__global__ __launch_bounds__(256) void pack_w_kernel(
    const float* __restrict__ coeffs,
    unsigned int* __restrict__ wp,
    float* __restrict__ scales)
{
    const int o = blockIdx.x;        // 0..255
    const int d = threadIdx.x;       // 0..255
    const float* cp = coeffs + ((size_t)o * DIM_D + d) * DIM_K;
    float4 c0 = *(const float4*)cp;
    float4 c1 = *(const float4*)(cp + 4);

    float m = fmaxf(fmaxf(fmaxf(fabsf(c0.x), fabsf(c0.y)),
                          fmaxf(fabsf(c0.z), fabsf(c0.w))),
                    fmaxf(fmaxf(fabsf(c1.x), fabsf(c1.y)),
                          fmaxf(fabsf(c1.z), fabsf(c1.w))));
    #pragma unroll
    for (int i = 32; i >= 1; i >>= 1)
        m = fmaxf(m, __shfl_xor(m, i));
    __shared__ float wm[4];
    if ((d & 63) == 0) wm[d >> 6] = m;
    __syncthreads();
    const float sc = fmaxf(fmaxf(fmaxf(wm[0], wm[1]), fmaxf(wm[2], wm[3])),
                           1e-30f);
    if (d == 0) scales[o] = sc;

    const float inv = 127.0f / sc;
    unsigned f0 = __float_as_uint(__builtin_fmaf(c0.x, inv, MAGIC));
    unsigned f1 = __float_as_uint(__builtin_fmaf(c0.y, inv, MAGIC));
    unsigned f2 = __float_as_uint(__builtin_fmaf(c0.z, inv, MAGIC));
    unsigned f3 = __float_as_uint(__builtin_fmaf(c0.w, inv, MAGIC));
    unsigned f4 = __float_as_uint(__builtin_fmaf(c1.x, inv, MAGIC));
    unsigned f5 = __float_as_uint(__builtin_fmaf(c1.y, inv, MAGIC));
    unsigned f6 = __float_as_uint(__builtin_fmaf(c1.z, inv, MAGIC));
    unsigned f7 = __float_as_uint(__builtin_fmaf(c1.w, inv, MAGIC));
    unsigned rA = __builtin_amdgcn_perm(f1, f0, 0x00000400u);
    unsigned rB = __builtin_amdgcn_perm(f3, f2, 0x00000400u);
    unsigned rC = __builtin_amdgcn_perm(f5, f4, 0x00000400u);
    unsigned rD = __builtin_amdgcn_perm(f7, f6, 0x00000400u);
    unsigned lo = __builtin_amdgcn_perm(rB, rA, 0x05040100u);
    unsigned hi = __builtin_amdgcn_perm(rD, rC, 0x05040100u);

    const int base = (((d >> 2) * 8 + (o >> 5)) * 64
                      + ((d >> 1) & 1) * 32 + (o & 31)) * 4 + (d & 1) * 2;
    wp[base]     = lo;
    wp[base + 1] = hi;
}

// tanh + Chebyshev -> 8 orders quantized+packed to 2 u32 (verified r11-r21)
__device__ __forceinline__ void cheb_q8(float xs, unsigned int* o2) {
    float e2 = __expf(2.f * xs);
    float r  = __builtin_amdgcn_rcpf(e2 + 1.f);
    float T1 = __builtin_fmaf(-2.f, r, 1.f);
    float tx = T1 + T1;
    float T2 = __builtin_fmaf(tx, T1, -1.f);
    float T3 = __builtin_fmaf(tx, T2, -T1);
    float T4 = __builtin_fmaf(tx, T3, -T2);
    float T5 = __builtin_fmaf(tx, T4, -T3);
    float T6 = __builtin_fmaf(tx, T5, -T4);
    float T7 = __builtin_fmaf(tx, T6, -T5);
    unsigned f1 = __float_as_uint(__builtin_fmaf(T1, 127.f, MAGIC));
    unsigned f2 = __float_as_uint(__builtin_fmaf(T2, 127.f, MAGIC));
    unsigned f3 = __float_as_uint(__builtin_fmaf(T3, 127.f, MAGIC));
    unsigned f4 = __float_as_uint(__builtin_fmaf(T4, 127.f, MAGIC));
    unsigned f5 = __float_as_uint(__builtin_fmaf(T5, 127.f, MAGIC));
    unsigned f6 = __float_as_uint(__builtin_fmaf(T6, 127.f, MAGIC));
    unsigned f7 = __float_as_uint(__builtin_fmaf(T7, 127.f, MAGIC));
    unsigned rA = __builtin_amdgcn_perm(f2, f1, 0x00000400u);
    unsigned rC = __builtin_amdgcn_perm(f5, f4, 0x00000400u);
    unsigned rD = __builtin_amdgcn_perm(f7, f6, 0x00000400u);
    o2[0] = __builtin_amdgcn_perm(f3, rA, 0x0401000Cu) | 127u;
    o2[1] = __builtin_amdgcn_perm(rD, rC, 0x05040100u);
}

// Producer/consumer wave specialization: waves 0-3 = MFMA consumers
// (col-split, no cheb), waves 4-7 = producers (cheb+LDS stage, no MFMA).
// HW round-robin -> 1 consumer + 1 producer per SIMD: producer VALU fills
// the consumer's MFMA-blocked cycles (m114 overlap; r4's concept, i8 fits).
__global__ __launch_bounds__(512, 2) void cfkan_kernel(
    const float* __restrict__ x,
    const i32x4* __restrict__ wp8,
    const float* __restrict__ scales,
    const float* __restrict__ bias,
    float* __restrict__ y)
{
    // double-buffered i8 A tile: [row][8 slots of 16B], slot XOR-swizzle; 32 KB
    __shared__ unsigned char Abuf[2][BM][128];

    const int t = threadIdx.x;
    const int wid = t >> 6;          // 0..7
    const bool cons = (wid < 4);     // consumer wave -> cols [64*wid, +64)
    const int l = t & 63;
    const int m = l & 31;            // A row / B,C col within 32-tile
    const int h = l >> 5;            // k-half: d-pair parity
    // XCD-aware bijective swizzle: grid 512 = 8 XCDs x 64 contiguous blocks
    const int bid = (int)blockIdx.x;
    const int cpx = (int)gridDim.x >> 3;
    const int row0 = ((bid & 7) * cpx + (bid >> 3)) * BM;
    // K-phase rotation (bit-identical: integer accumulate is exact/commutative)
    const int ph = bid & 15;

    // ---- consumer state ----
    i32x16 acc[4][2];
    i32x4 bq[NSTEP + 2][2];          // 2-deep B pipeline
    i32x4 ra[4], rb[4];              // ping-pong A-frag banks

    // ---- producer state ----
    const int pt   = t & 255;        // producer thread 0..255
    const int lrow = pt >> 1;        // row staged (0..127)
    const int half = pt & 1;         // which 8 of the 16 chunk-d's
    const float* xrow = x + (size_t)(row0 + lrow) * DIM_D + half * 8;
    float xv[8];

// A-frag read: step S, lane -> rows rt*32+m, slot (2S+h), XOR by row&7
#define READA(DST, AB, S) do {                                             \
    const int _so = (((2 * (S) + h) ^ (m & 7)) * 16);                      \
    DST[0] = *(const i32x4*)&AB[      m][_so];                             \
    DST[1] = *(const i32x4*)&AB[ 32 + m][_so];                             \
    DST[2] = *(const i32x4*)&AB[ 64 + m][_so];                             \
    DST[3] = *(const i32x4*)&AB[ 96 + m][_so];                             \
} while (0)
#define LOADB2(DST, SG) do {                                               \
    DST[0] = wp8[((SG) * 8 + wid * 2 + 0) * 64 + l];                       \
    DST[1] = wp8[((SG) * 8 + wid * 2 + 1) * 64 + l];                       \
} while (0)
// stage d-pair {2S, 2S+1}: one swizzled ds_write_b128
#define STAGE2(ANX, S, X0, X1) do {                                        \
    union { unsigned int u[4]; i32x4 v; } _tv;                             \
    cheb_q8(X0, &_tv.u[0]);                                                \
    cheb_q8(X1, &_tv.u[2]);                                                \
    *(i32x4*)&ANX[lrow][(((half * 4 + (S)) ^ (lrow & 7)) * 16)] = _tv.v;   \
} while (0)
// barrier draining ONLY LDS ops; global loads stay in flight (T4)
#define SOFT_BARRIER() do {                                                \
    asm volatile("s_waitcnt lgkmcnt(0)" ::: "memory");                     \
    __builtin_amdgcn_s_barrier();                                          \
    __builtin_amdgcn_sched_barrier(0);                                     \
} while (0)
// consumer step: ping-pong A banks, 2-deep B, setprio (role-split -> T5 pays)
#define STEPC(CUR, NXT, S, DO_READ) do {                                   \
    const int _tgt = ((S) < 2) ? (cc4 + (S) + 2) : (nc4 + (S) - 2);        \
    LOADB2(bq[(S) + 2], _tgt);                                             \
    if (DO_READ) READA(NXT, A, (S) + 1);                                   \
    __builtin_amdgcn_s_setprio(1);                                         \
    _Pragma("unroll")                                                      \
    for (int _rt = 0; _rt < 4; ++_rt) {                                    \
        acc[_rt][0] = __builtin_amdgcn_mfma_i32_32x32x32_i8(               \
            CUR[_rt], bq[S][0], acc[_rt][0], 0, 0, 0);                     \
        acc[_rt][1] = __builtin_amdgcn_mfma_i32_32x32x32_i8(               \
            CUR[_rt], bq[S][1], acc[_rt][1], 0, 0, 0);                     \
    }                                                                      \
    __builtin_amdgcn_s_setprio(0);                                         \
} while (0)

    // ---- prologue ----
    if (cons) {
        #pragma unroll
        for (int rt = 0; rt < 4; ++rt)
            #pragma unroll
            for (int ct = 0; ct < 2; ++ct)
                #pragma unroll
                for (int qi = 0; qi < 16; ++qi)
                    acc[rt][ct][qi] = 0;
        LOADB2(bq[0], ph * 4);
        LOADB2(bq[1], ph * 4 + 1);
    } else {
        float4 a0 = *(const float4*)(xrow + ph * 16);
        float4 a1 = *(const float4*)(xrow + ph * 16 + 4);
        float xs[8] = {a0.x, a0.y, a0.z, a0.w, a1.x, a1.y, a1.z, a1.w};
        #pragma unroll
        for (int s = 0; s < 4; ++s)
            STAGE2(Abuf[0], s, xs[2 * s], xs[2 * s + 1]);
        const int c1 = (ph + 1) & 15;
        float4 b0 = *(const float4*)(xrow + c1 * 16);
        float4 b1 = *(const float4*)(xrow + c1 * 16 + 4);
        xv[0] = b0.x; xv[1] = b0.y; xv[2] = b0.z; xv[3] = b0.w;
        xv[4] = b1.x; xv[5] = b1.y; xv[6] = b1.z; xv[7] = b1.w;
    }
    SOFT_BARRIER();
    if (cons) READA(ra, Abuf[0], 0);

    // ---- main loop: one barrier per chunk; roles fixed per wave ----
    #pragma unroll 1
    for (int ci = 0; ci < NCHUNK; ++ci) {
        const unsigned char (*A)[128] = Abuf[ci & 1];
        unsigned char (*ANX)[128]     = Abuf[(ci & 1) ^ 1];

        if (cons) {
            const int cc  = (ci + ph) & 15;
            const int ncc = (ci + 1 + ph) & 15;
            const int cc4 = cc * 4, nc4 = ncc * 4;
            STEPC(ra, rb, 0, true);
            STEPC(rb, ra, 1, true);
            STEPC(ra, rb, 2, true);
            STEPC(rb, ra, 3, false);
            bq[0][0] = bq[4][0]; bq[0][1] = bq[4][1];   // carry pipeline
            bq[1][0] = bq[5][0]; bq[1][1] = bq[5][1];
        } else {
            float4 xn0, xn1;
            if (ci + 2 < NCHUNK) {
                const int c2 = (ci + 2 + ph) & 15;
                xn0 = *(const float4*)(xrow + c2 * 16);
                xn1 = *(const float4*)(xrow + c2 * 16 + 4);
            }
            if (ci < NCHUNK - 1) {
                STAGE2(ANX, 0, xv[0], xv[1]);
                STAGE2(ANX, 1, xv[2], xv[3]);
                STAGE2(ANX, 2, xv[4], xv[5]);
                STAGE2(ANX, 3, xv[6], xv[7]);
            }
            if (ci + 2 < NCHUNK) {
                xv[0] = xn0.x; xv[1] = xn0.y; xv[2] = xn0.z; xv[3] = xn0.w;
                xv[4] = xn1.x; xv[5] = xn1.y; xv[6] = xn1.z; xv[7] = xn1.w;
            }
        }

        SOFT_BARRIER();
        if (cons && ci < NCHUNK - 1) READA(ra, ANX, 0); // next chunk's step-0
    }

    // ---- epilogue (consumers only): per-column scale, bias, store f32 ----
    // C/D 32x32: col = lane&31, row = (qi&3) + 8*(qi>>2) + 4*(lane>>5)
    if (cons) {
        #pragma unroll
        for (int ct = 0; ct < 2; ++ct) {
            const int col = wid * 64 + ct * 32 + m;
            const float sf = scales[col] * (1.f / 16129.f);   // s_o / 127^2
            const float bv = bias[col];
            #pragma unroll
            for (int rt = 0; rt < 4; ++rt) {
                #pragma unroll
                for (int qi = 0; qi < 16; ++qi) {
                    const int grow = row0 + rt * 32
                                   + (qi & 3) + 8 * (qi >> 2) + 4 * h;
                    y[(size_t)grow * DIM_O + col] =
                        __builtin_fmaf((float)acc[rt][ct][qi], sf, bv);
                }
            }
        }
    }
#undef READA
#undef LOADB2
#undef STAGE2
#undef SOFT_BARRIER
#undef STEPC
}

extern "C" void kernel_launch(void* const* d_in, const int* in_sizes, int n_in,
                              void* d_out, int out_size, void* d_ws, size_t ws_size,
                              hipStream_t stream) {
    const float* x      = (const float*)d_in[0];
    const float* coeffs = (const float*)d_in[1];
    const float* bias   = (const float*)d_in[2];
    float* y = (float*)d_out;
    float*        scales = (float*)d_ws;                      // 1 KB
    unsigned int* wp     = (unsigned int*)((char*)d_ws + 1024); // 512 KB

    const int n_tokens = in_sizes[0] / DIM_D;     // 65536

    pack_w_kernel<<<DIM_O, 256, 0, stream>>>(coeffs, wp, scales);
    cfkan_kernel<<<n_tokens / BM, 512, 0, stream>>>(
        x, (const i32x4*)wp, scales, bias, y);
}

// Round 23
// 53.316 us; speedup vs baseline: 1.1261x; 1.1261x over previous
//
#include <hip/hip_runtime.h>
#include <hip/hip_bf16.h>

typedef __attribute__((ext_vector_type(4)))  int   i32x4;
typedef __attribute__((ext_vector_type(16))) int   i32x16;

#define DIM_D 256
#define DIM_O 256
#define DIM_K 8
#define BM 128
#define NCHUNK 16                 // 16 chunks of 16 d-values
#define NSTEP 4                   // 4 K=32 steps per chunk (4 d's each)
#define MAGIC 12582912.f          // 1.5 * 2^23 : fma+byte-extract = rint to int8

// ---- pack kernel: one block per output row o (verified r12-r22) ----
// Per-o scale s_o = max|c[o,:,:]|, quantize into 32x32x32 i8 MFMA B-frag order:
// byte addr = ((s*8 + ct)*64 + lane)*16 + j, where for (o,d,k):
//   s = d>>2, ct = o>>5, lane = ((d>>1)&1)*32 + (o&31), j = (d&1)*8 + k
__global__ __launch_bounds__(256) void pack_w_kernel(
    const float* __restrict__ coeffs,
    unsigned int* __restrict__ wp,
    float* __restrict__ scales)
{
    const int o = blockIdx.x;        // 0..255
    const int d = threadIdx.x;       // 0..255
    const float* cp = coeffs + ((size_t)o * DIM_D + d) * DIM_K;
    float4 c0 = *(const float4*)cp;
    float4 c1 = *(const float4*)(cp + 4);

    float m = fmaxf(fmaxf(fmaxf(fabsf(c0.x), fabsf(c0.y)),
                          fmaxf(fabsf(c0.z), fabsf(c0.w))),
                    fmaxf(fmaxf(fabsf(c1.x), fabsf(c1.y)),
                          fmaxf(fabsf(c1.z), fabsf(c1.w))));
    #pragma unroll
    for (int i = 32; i >= 1; i >>= 1)
        m = fmaxf(m, __shfl_xor(m, i));
    __shared__ float wm[4];
    if ((d & 63) == 0) wm[d >> 6] = m;
    __syncthreads();
    const float sc = fmaxf(fmaxf(fmaxf(wm[0], wm[1]), fmaxf(wm[2], wm[3])),
                           1e-30f);
    if (d == 0) scales[o] = sc;

    const float inv = 127.0f / sc;
    unsigned f0 = __float_as_uint(__builtin_fmaf(c0.x, inv, MAGIC));
    unsigned f1 = __float_as_uint(__builtin_fmaf(c0.y, inv, MAGIC));
    unsigned f2 = __float_as_uint(__builtin_fmaf(c0.z, inv, MAGIC));
    unsigned f3 = __float_as_uint(__builtin_fmaf(c0.w, inv, MAGIC));
    unsigned f4 = __float_as_uint(__builtin_fmaf(c1.x, inv, MAGIC));
    unsigned f5 = __float_as_uint(__builtin_fmaf(c1.y, inv, MAGIC));
    unsigned f6 = __float_as_uint(__builtin_fmaf(c1.z, inv, MAGIC));
    unsigned f7 = __float_as_uint(__builtin_fmaf(c1.w, inv, MAGIC));
    unsigned rA = __builtin_amdgcn_perm(f1, f0, 0x00000400u);
    unsigned rB = __builtin_amdgcn_perm(f3, f2, 0x00000400u);
    unsigned rC = __builtin_amdgcn_perm(f5, f4, 0x00000400u);
    unsigned rD = __builtin_amdgcn_perm(f7, f6, 0x00000400u);
    unsigned lo = __builtin_amdgcn_perm(rB, rA, 0x05040100u);
    unsigned hi = __builtin_amdgcn_perm(rD, rC, 0x05040100u);

    const int base = (((d >> 2) * 8 + (o >> 5)) * 64
                      + ((d >> 1) & 1) * 32 + (o & 31)) * 4 + (d & 1) * 2;
    wp[base]     = lo;
    wp[base + 1] = hi;
}

// tanh + Chebyshev -> 8 orders quantized+packed to 2 u32 (verified r11-r22)
__device__ __forceinline__ void cheb_q8(float xs, unsigned int* o2) {
    float e2 = __expf(2.f * xs);
    float r  = __builtin_amdgcn_rcpf(e2 + 1.f);
    float T1 = __builtin_fmaf(-2.f, r, 1.f);
    float tx = T1 + T1;
    float T2 = __builtin_fmaf(tx, T1, -1.f);
    float T3 = __builtin_fmaf(tx, T2, -T1);
    float T4 = __builtin_fmaf(tx, T3, -T2);
    float T5 = __builtin_fmaf(tx, T4, -T3);
    float T6 = __builtin_fmaf(tx, T5, -T4);
    float T7 = __builtin_fmaf(tx, T6, -T5);
    unsigned f1 = __float_as_uint(__builtin_fmaf(T1, 127.f, MAGIC));
    unsigned f2 = __float_as_uint(__builtin_fmaf(T2, 127.f, MAGIC));
    unsigned f3 = __float_as_uint(__builtin_fmaf(T3, 127.f, MAGIC));
    unsigned f4 = __float_as_uint(__builtin_fmaf(T4, 127.f, MAGIC));
    unsigned f5 = __float_as_uint(__builtin_fmaf(T5, 127.f, MAGIC));
    unsigned f6 = __float_as_uint(__builtin_fmaf(T6, 127.f, MAGIC));
    unsigned f7 = __float_as_uint(__builtin_fmaf(T7, 127.f, MAGIC));
    unsigned rA = __builtin_amdgcn_perm(f2, f1, 0x00000400u);
    unsigned rC = __builtin_amdgcn_perm(f5, f4, 0x00000400u);
    unsigned rD = __builtin_amdgcn_perm(f7, f6, 0x00000400u);
    o2[0] = __builtin_amdgcn_perm(f3, rA, 0x0401000Cu) | 127u;
    o2[1] = __builtin_amdgcn_perm(rD, rC, 0x05040100u);
}

__global__ __launch_bounds__(256, 2) void cfkan_kernel(
    const float* __restrict__ x,
    const i32x4* __restrict__ wp8,
    const float* __restrict__ scales,
    const float* __restrict__ bias,
    float* __restrict__ y)
{
    // double-buffered i8 A tile: [row][8 slots of 16B], slot XOR-swizzle; 32 KB
    __shared__ unsigned char Abuf[2][BM][128];

    const int t = threadIdx.x;
    const int w = t >> 6;            // wave 0..3 -> output cols [64w, 64w+64)
    const int l = t & 63;
    const int m = l & 31;            // A row / B,C col within 32-tile
    const int h = l >> 5;            // k-half: d-pair parity
    // XCD-aware bijective swizzle: grid 512 = 8 XCDs x 64 contiguous blocks
    const int bid = (int)blockIdx.x;
    const int cpx = (int)gridDim.x >> 3;
    const int row0 = ((bid & 7) * cpx + (bid >> 3)) * BM;
    // K-phase rotation (bit-identical: integer accumulate is exact/commutative)
    const int ph = bid & 15;

    // Temporal de-phasing: with 512 blocks on 256 CUs, bid and bid+256 are
    // the likely co-residents. Identical blocks launched together stay
    // barrier-phase-locked (stall together, contend together). Delay the
    // second co-resident by ~half a de-locked chunk period so its VALU
    // phase overlaps the other's MFMA phase. One-time ~1730 cyc, exact-math.
    if (bid >= ((int)gridDim.x >> 1)) {
        __builtin_amdgcn_s_sleep(13);   // ~13*64*2 ≈ 1700 cyc (2 sleeps)
        __builtin_amdgcn_s_sleep(14);
    }

    i32x16 acc[4][2];
    #pragma unroll
    for (int rt = 0; rt < 4; ++rt)
        #pragma unroll
        for (int ct = 0; ct < 2; ++ct)
            #pragma unroll
            for (int qi = 0; qi < 16; ++qi)
                acc[rt][ct][qi] = 0;

    const int lrow = t >> 1;         // 0..127 (row this thread stages)
    const int half = t & 1;          // which 8 of the 16 chunk-d's
    const float* xrow = x + (size_t)(row0 + lrow) * DIM_D + half * 8;

// A-frag read: step S, lane -> rows rt*32+m, slot (2S+h), XOR by row&7
#define READA(DST, AB, S) do {                                             \
    const int _so = (((2 * (S) + h) ^ (m & 7)) * 16);                      \
    DST[0] = *(const i32x4*)&AB[      m][_so];                             \
    DST[1] = *(const i32x4*)&AB[ 32 + m][_so];                             \
    DST[2] = *(const i32x4*)&AB[ 64 + m][_so];                             \
    DST[3] = *(const i32x4*)&AB[ 96 + m][_so];                             \
} while (0)
#define LOADB2(DST, SG) do {                                               \
    DST[0] = wp8[((SG) * 8 + w * 2 + 0) * 64 + l];                         \
    DST[1] = wp8[((SG) * 8 + w * 2 + 1) * 64 + l];                         \
} while (0)
// stage d-pair {2S, 2S+1} of the staged chunk: one swizzled ds_write_b128
#define STAGE2(ANX, S, X0, X1) do {                                        \
    union { unsigned int u[4]; i32x4 v; } _tv;                             \
    cheb_q8(X0, &_tv.u[0]);                                                \
    cheb_q8(X1, &_tv.u[2]);                                                \
    *(i32x4*)&ANX[lrow][(((half * 4 + (S)) ^ (lrow & 7)) * 16)] = _tv.v;   \
} while (0)
// barrier draining ONLY LDS ops; global loads stay in flight (T4)
#define SOFT_BARRIER() do {                                                \
    asm volatile("s_waitcnt lgkmcnt(0)" ::: "memory");                     \
    __builtin_amdgcn_s_barrier();                                          \
    __builtin_amdgcn_sched_barrier(0);                                     \
} while (0)

    // ---- prologue: stage chunk ph; preload x(ph+1) + B(first 2 steps) ----
    float xv[8];
    {
        float4 a0 = *(const float4*)(xrow + ph * 16);
        float4 a1 = *(const float4*)(xrow + ph * 16 + 4);
        float xs[8] = {a0.x, a0.y, a0.z, a0.w, a1.x, a1.y, a1.z, a1.w};
        #pragma unroll
        for (int s = 0; s < 4; ++s)
            STAGE2(Abuf[0], s, xs[2 * s], xs[2 * s + 1]);
        const int c1 = (ph + 1) & 15;
        float4 b0 = *(const float4*)(xrow + c1 * 16);
        float4 b1 = *(const float4*)(xrow + c1 * 16 + 4);
        xv[0] = b0.x; xv[1] = b0.y; xv[2] = b0.z; xv[3] = b0.w;
        xv[4] = b1.x; xv[5] = b1.y; xv[6] = b1.z; xv[7] = b1.w;
    }
    i32x4 bq[NSTEP + 2][2];          // 2-deep B pipeline (static idx via unroll)
    LOADB2(bq[0], ph * 4);
    LOADB2(bq[1], ph * 4 + 1);
    SOFT_BARRIER();
    i32x4 r[4], rn[4];
    READA(r, Abuf[0], 0);

    // ---- main loop: 4 K=32 steps/chunk, fine interleave, soft barrier ----
    #pragma unroll 1
    for (int ci = 0; ci < NCHUNK; ++ci) {
        const int cc  = (ci + ph) & 15;       // chunk processed this iter
        const int ncc = (ci + 1 + ph) & 15;   // chunk staged this iter
        const unsigned char (*A)[128] = Abuf[ci & 1];
        unsigned char (*ANX)[128]     = Abuf[(ci & 1) ^ 1];
        const bool stage = (ci < NCHUNK - 1);
        float4 xn0, xn1;
        if (ci + 2 < NCHUNK) {
            const int c2 = (ci + 2 + ph) & 15;
            xn0 = *(const float4*)(xrow + c2 * 16);
            xn1 = *(const float4*)(xrow + c2 * 16 + 4);
        }
        const int cc4 = cc * 4, nc4 = ncc * 4;

        #pragma unroll
        for (int s = 0; s < NSTEP; ++s) {
            // 2-steps-ahead B prefetch, following the rotated sequence
            const int tgt = (s < 2) ? (cc4 + s + 2) : (nc4 + s - 2);
            LOADB2(bq[s + 2], tgt);
            if (s < NSTEP - 1) READA(rn, A, s + 1);

            __builtin_amdgcn_s_setprio(1);
            #pragma unroll
            for (int rt = 0; rt < 4; ++rt) {
                acc[rt][0] = __builtin_amdgcn_mfma_i32_32x32x32_i8(
                    r[rt], bq[s][0], acc[rt][0], 0, 0, 0);
                acc[rt][1] = __builtin_amdgcn_mfma_i32_32x32x32_i8(
                    r[rt], bq[s][1], acc[rt][1], 0, 0, 0);
            }
            __builtin_amdgcn_s_setprio(0);

            if (stage) STAGE2(ANX, s, xv[2 * s], xv[2 * s + 1]);

            if (s < NSTEP - 1) { r[0] = rn[0]; r[1] = rn[1]; r[2] = rn[2]; r[3] = rn[3]; }
        }
        bq[0][0] = bq[4][0]; bq[0][1] = bq[4][1];     // carry the pipeline
        bq[1][0] = bq[5][0]; bq[1][1] = bq[5][1];
        if (ci + 2 < NCHUNK) {
            xv[0] = xn0.x; xv[1] = xn0.y; xv[2] = xn0.z; xv[3] = xn0.w;
            xv[4] = xn1.x; xv[5] = xn1.y; xv[6] = xn1.z; xv[7] = xn1.w;
        }
        SOFT_BARRIER();
        if (ci < NCHUNK - 1) READA(r, ANX, 0);        // next chunk's step-0 frags
    }

    // ---- epilogue: per-column scale, add bias, store f32 ----
    // C/D 32x32: col = lane&31, row = (qi&3) + 8*(qi>>2) + 4*(lane>>5)
    #pragma unroll
    for (int ct = 0; ct < 2; ++ct) {
        const int col = w * 64 + ct * 32 + m;
        const float sf = scales[col] * (1.f / 16129.f);   // s_o / 127^2
        const float bv = bias[col];
        #pragma unroll
        for (int rt = 0; rt < 4; ++rt) {
            #pragma unroll
            for (int qi = 0; qi < 16; ++qi) {
                const int grow = row0 + rt * 32 + (qi & 3) + 8 * (qi >> 2) + 4 * h;
                y[(size_t)grow * DIM_O + col] =
                    __builtin_fmaf((float)acc[rt][ct][qi], sf, bv);
            }
        }
    }
#undef READA
#undef LOADB2
#undef STAGE2
#undef SOFT_BARRIER
}

extern "C" void kernel_launch(void* const* d_in, const int* in_sizes, int n_in,
                              void* d_out, int out_size, void* d_ws, size_t ws_size,
                              hipStream_t stream) {
    const float* x      = (const float*)d_in[0];
    const float* coeffs = (const float*)d_in[1];
    const float* bias   = (const float*)d_in[2];
    float* y = (float*)d_out;
    float*        scales = (float*)d_ws;                      // 1 KB
    unsigned int* wp     = (unsigned int*)((char*)d_ws + 1024); // 512 KB

    const int n_tokens = in_sizes[0] / DIM_D;     // 65536

    pack_w_kernel<<<DIM_O, 256, 0, stream>>>(coeffs, wp, scales);
    cfkan_kernel<<<n_tokens / BM, 256, 0, stream>>>(
        x, (const i32x4*)wp, scales, bias, y);
}

// Round 24
// 53.223 us; speedup vs baseline: 1.1281x; 1.0017x over previous
//
#include <hip/hip_runtime.h>
#include <hip/hip_bf16.h>

typedef __attribute__((ext_vector_type(4)))  int   i32x4;
typedef __attribute__((ext_vector_type(16))) int   i32x16;

#define DIM_D 256
#define DIM_O 256
#define DIM_K 8
#define BM 128
#define NCHUNK 16                 // 16 chunks of 16 d-values
#define NSTEP 4                   // 4 K=32 steps per chunk (4 d's each)
#define MAGIC 12582912.f          // 1.5 * 2^23 : fma+byte-extract = rint to int8

// ---- pack kernel: one block per output row o (verified r12-r23) ----
// Per-o scale s_o = max|c[o,:,:]|, quantize into 32x32x32 i8 MFMA B-frag order:
// byte addr = ((s*8 + ct)*64 + lane)*16 + j, where for (o,d,k):
//   s = d>>2, ct = o>>5, lane = ((d>>1)&1)*32 + (o&31), j = (d&1)*8 + k
__global__ __launch_bounds__(256) void pack_w_kernel(
    const float* __restrict__ coeffs,
    unsigned int* __restrict__ wp,
    float* __restrict__ scales)
{
    const int o = blockIdx.x;        // 0..255
    const int d = threadIdx.x;       // 0..255
    const float* cp = coeffs + ((size_t)o * DIM_D + d) * DIM_K;
    float4 c0 = *(const float4*)cp;
    float4 c1 = *(const float4*)(cp + 4);

    float m = fmaxf(fmaxf(fmaxf(fabsf(c0.x), fabsf(c0.y)),
                          fmaxf(fabsf(c0.z), fabsf(c0.w))),
                    fmaxf(fmaxf(fabsf(c1.x), fabsf(c1.y)),
                          fmaxf(fabsf(c1.z), fabsf(c1.w))));
    #pragma unroll
    for (int i = 32; i >= 1; i >>= 1)
        m = fmaxf(m, __shfl_xor(m, i));
    __shared__ float wm[4];
    if ((d & 63) == 0) wm[d >> 6] = m;
    __syncthreads();
    const float sc = fmaxf(fmaxf(fmaxf(wm[0], wm[1]), fmaxf(wm[2], wm[3])),
                           1e-30f);
    if (d == 0) scales[o] = sc;

    const float inv = 127.0f / sc;
    unsigned f0 = __float_as_uint(__builtin_fmaf(c0.x, inv, MAGIC));
    unsigned f1 = __float_as_uint(__builtin_fmaf(c0.y, inv, MAGIC));
    unsigned f2 = __float_as_uint(__builtin_fmaf(c0.z, inv, MAGIC));
    unsigned f3 = __float_as_uint(__builtin_fmaf(c0.w, inv, MAGIC));
    unsigned f4 = __float_as_uint(__builtin_fmaf(c1.x, inv, MAGIC));
    unsigned f5 = __float_as_uint(__builtin_fmaf(c1.y, inv, MAGIC));
    unsigned f6 = __float_as_uint(__builtin_fmaf(c1.z, inv, MAGIC));
    unsigned f7 = __float_as_uint(__builtin_fmaf(c1.w, inv, MAGIC));
    unsigned rA = __builtin_amdgcn_perm(f1, f0, 0x00000400u);
    unsigned rB = __builtin_amdgcn_perm(f3, f2, 0x00000400u);
    unsigned rC = __builtin_amdgcn_perm(f5, f4, 0x00000400u);
    unsigned rD = __builtin_amdgcn_perm(f7, f6, 0x00000400u);
    unsigned lo = __builtin_amdgcn_perm(rB, rA, 0x05040100u);
    unsigned hi = __builtin_amdgcn_perm(rD, rC, 0x05040100u);

    const int base = (((d >> 2) * 8 + (o >> 5)) * 64
                      + ((d >> 1) & 1) * 32 + (o & 31)) * 4 + (d & 1) * 2;
    wp[base]     = lo;
    wp[base + 1] = hi;
}

// tanh + Chebyshev -> 8 orders quantized+packed to 2 u32 (verified r11-r23)
__device__ __forceinline__ void cheb_q8(float xs, unsigned int* o2) {
    float e2 = __expf(2.f * xs);
    float r  = __builtin_amdgcn_rcpf(e2 + 1.f);
    float T1 = __builtin_fmaf(-2.f, r, 1.f);
    float tx = T1 + T1;
    float T2 = __builtin_fmaf(tx, T1, -1.f);
    float T3 = __builtin_fmaf(tx, T2, -T1);
    float T4 = __builtin_fmaf(tx, T3, -T2);
    float T5 = __builtin_fmaf(tx, T4, -T3);
    float T6 = __builtin_fmaf(tx, T5, -T4);
    float T7 = __builtin_fmaf(tx, T6, -T5);
    unsigned f1 = __float_as_uint(__builtin_fmaf(T1, 127.f, MAGIC));
    unsigned f2 = __float_as_uint(__builtin_fmaf(T2, 127.f, MAGIC));
    unsigned f3 = __float_as_uint(__builtin_fmaf(T3, 127.f, MAGIC));
    unsigned f4 = __float_as_uint(__builtin_fmaf(T4, 127.f, MAGIC));
    unsigned f5 = __float_as_uint(__builtin_fmaf(T5, 127.f, MAGIC));
    unsigned f6 = __float_as_uint(__builtin_fmaf(T6, 127.f, MAGIC));
    unsigned f7 = __float_as_uint(__builtin_fmaf(T7, 127.f, MAGIC));
    unsigned rA = __builtin_amdgcn_perm(f2, f1, 0x00000400u);
    unsigned rC = __builtin_amdgcn_perm(f5, f4, 0x00000400u);
    unsigned rD = __builtin_amdgcn_perm(f7, f6, 0x00000400u);
    o2[0] = __builtin_amdgcn_perm(f3, rA, 0x0401000Cu) | 127u;
    o2[1] = __builtin_amdgcn_perm(rD, rC, 0x05040100u);
}

__global__ __launch_bounds__(256, 2) void cfkan_kernel(
    const float* __restrict__ x,
    const i32x4* __restrict__ wp8,
    const float* __restrict__ scales,
    const float* __restrict__ bias,
    float* __restrict__ y)
{
    // double-buffered i8 A tile: [row][8 slots of 16B], slot XOR-swizzle; 32 KB
    __shared__ unsigned char Abuf[2][BM][128];

    const int t = threadIdx.x;
    const int w = t >> 6;            // wave 0..3 -> output cols [64w, 64w+64)
    const int l = t & 63;
    const int m = l & 31;            // A row / B,C col within 32-tile
    const int h = l >> 5;            // k-half: d-pair parity
    // XCD-aware bijective swizzle: grid 512 = 8 XCDs x 64 contiguous blocks
    const int bid = (int)blockIdx.x;
    const int cpx = (int)gridDim.x >> 3;
    const int row0 = ((bid & 7) * cpx + (bid >> 3)) * BM;
    // K-phase rotation, co-resident-decorrelated: pairs (bid, bid+256) share
    // a SIMD; ensure they get DIFFERENT phases (bit-identical output:
    // integer accumulation is exact and order-independent)
    const int ph = (bid + (bid >> 8) * 5) & 15;

    // Temporal de-phasing: delay the second co-resident (bid>=256) by
    // ~half a chunk period (~3500 cyc) so its VALU/stage phase overlaps
    // the partner's MFMA phase instead of lockstepping with it.
    if (bid & 256)
        __builtin_amdgcn_s_sleep(55);   // ~55*64 ≈ 3520 cyc

    i32x16 acc[4][2];
    #pragma unroll
    for (int rt = 0; rt < 4; ++rt)
        #pragma unroll
        for (int ct = 0; ct < 2; ++ct)
            #pragma unroll
            for (int qi = 0; qi < 16; ++qi)
                acc[rt][ct][qi] = 0;

    const int lrow = t >> 1;         // 0..127 (row this thread stages)
    const int half = t & 1;          // which 8 of the 16 chunk-d's
    const float* xrow = x + (size_t)(row0 + lrow) * DIM_D + half * 8;

// A-frag read: step S, lane -> rows rt*32+m, slot (2S+h), XOR by row&7
#define READA(DST, AB, S) do {                                             \
    const int _so = (((2 * (S) + h) ^ (m & 7)) * 16);                      \
    DST[0] = *(const i32x4*)&AB[      m][_so];                             \
    DST[1] = *(const i32x4*)&AB[ 32 + m][_so];                             \
    DST[2] = *(const i32x4*)&AB[ 64 + m][_so];                             \
    DST[3] = *(const i32x4*)&AB[ 96 + m][_so];                             \
} while (0)
#define LOADB2(DST, SG) do {                                               \
    DST[0] = wp8[((SG) * 8 + w * 2 + 0) * 64 + l];                         \
    DST[1] = wp8[((SG) * 8 + w * 2 + 1) * 64 + l];                         \
} while (0)
// stage d-pair {2S, 2S+1} of the staged chunk: one swizzled ds_write_b128
#define STAGE2(ANX, S, X0, X1) do {                                        \
    union { unsigned int u[4]; i32x4 v; } _tv;                             \
    cheb_q8(X0, &_tv.u[0]);                                                \
    cheb_q8(X1, &_tv.u[2]);                                                \
    *(i32x4*)&ANX[lrow][(((half * 4 + (S)) ^ (lrow & 7)) * 16)] = _tv.v;   \
} while (0)
// barrier draining ONLY LDS ops; global loads stay in flight (T4)
#define SOFT_BARRIER() do {                                                \
    asm volatile("s_waitcnt lgkmcnt(0)" ::: "memory");                     \
    __builtin_amdgcn_s_barrier();                                          \
    __builtin_amdgcn_sched_barrier(0);                                     \
} while (0)

    // ---- prologue: stage chunk ph; preload x(ph+1) + B(first 2 steps) ----
    float xv[8];
    {
        float4 a0 = *(const float4*)(xrow + ph * 16);
        float4 a1 = *(const float4*)(xrow + ph * 16 + 4);
        float xs[8] = {a0.x, a0.y, a0.z, a0.w, a1.x, a1.y, a1.z, a1.w};
        #pragma unroll
        for (int s = 0; s < 4; ++s)
            STAGE2(Abuf[0], s, xs[2 * s], xs[2 * s + 1]);
        const int c1 = (ph + 1) & 15;
        float4 b0 = *(const float4*)(xrow + c1 * 16);
        float4 b1 = *(const float4*)(xrow + c1 * 16 + 4);
        xv[0] = b0.x; xv[1] = b0.y; xv[2] = b0.z; xv[3] = b0.w;
        xv[4] = b1.x; xv[5] = b1.y; xv[6] = b1.z; xv[7] = b1.w;
    }
    i32x4 bq[NSTEP + 2][2];          // 2-deep B pipeline (static idx via unroll)
    LOADB2(bq[0], ph * 4);
    LOADB2(bq[1], ph * 4 + 1);
    SOFT_BARRIER();
    i32x4 r[4], rn[4];
    READA(r, Abuf[0], 0);

    // ---- main loop: 4 K=32 steps/chunk, fine interleave, soft barrier ----
    #pragma unroll 1
    for (int ci = 0; ci < NCHUNK; ++ci) {
        const int cc  = (ci + ph) & 15;       // chunk processed this iter
        const int ncc = (ci + 1 + ph) & 15;   // chunk staged this iter
        const unsigned char (*A)[128] = Abuf[ci & 1];
        unsigned char (*ANX)[128]     = Abuf[(ci & 1) ^ 1];
        const bool stage = (ci < NCHUNK - 1);
        float4 xn0, xn1;
        if (ci + 2 < NCHUNK) {
            const int c2 = (ci + 2 + ph) & 15;
            xn0 = *(const float4*)(xrow + c2 * 16);
            xn1 = *(const float4*)(xrow + c2 * 16 + 4);
        }
        const int cc4 = cc * 4, nc4 = ncc * 4;

        #pragma unroll
        for (int s = 0; s < NSTEP; ++s) {
            // 2-steps-ahead B prefetch, following the rotated sequence
            const int tgt = (s < 2) ? (cc4 + s + 2) : (nc4 + s - 2);
            LOADB2(bq[s + 2], tgt);
            if (s < NSTEP - 1) READA(rn, A, s + 1);

            __builtin_amdgcn_s_setprio(1);
            #pragma unroll
            for (int rt = 0; rt < 4; ++rt) {
                acc[rt][0] = __builtin_amdgcn_mfma_i32_32x32x32_i8(
                    r[rt], bq[s][0], acc[rt][0], 0, 0, 0);
                acc[rt][1] = __builtin_amdgcn_mfma_i32_32x32x32_i8(
                    r[rt], bq[s][1], acc[rt][1], 0, 0, 0);
            }
            __builtin_amdgcn_s_setprio(0);

            if (stage) STAGE2(ANX, s, xv[2 * s], xv[2 * s + 1]);

            if (s < NSTEP - 1) { r[0] = rn[0]; r[1] = rn[1]; r[2] = rn[2]; r[3] = rn[3]; }
        }
        bq[0][0] = bq[4][0]; bq[0][1] = bq[4][1];     // carry the pipeline
        bq[1][0] = bq[5][0]; bq[1][1] = bq[5][1];
        if (ci + 2 < NCHUNK) {
            xv[0] = xn0.x; xv[1] = xn0.y; xv[2] = xn0.z; xv[3] = xn0.w;
            xv[4] = xn1.x; xv[5] = xn1.y; xv[6] = xn1.z; xv[7] = xn1.w;
        }
        SOFT_BARRIER();
        if (ci < NCHUNK - 1) READA(r, ANX, 0);        // next chunk's step-0 frags
    }

    // ---- epilogue: per-column scale, add bias, store f32 ----
    // C/D 32x32: col = lane&31, row = (qi&3) + 8*(qi>>2) + 4*(lane>>5)
    #pragma unroll
    for (int ct = 0; ct < 2; ++ct) {
        const int col = w * 64 + ct * 32 + m;
        const float sf = scales[col] * (1.f / 16129.f);   // s_o / 127^2
        const float bv = bias[col];
        #pragma unroll
        for (int rt = 0; rt < 4; ++rt) {
            #pragma unroll
            for (int qi = 0; qi < 16; ++qi) {
                const int grow = row0 + rt * 32 + (qi & 3) + 8 * (qi >> 2) + 4 * h;
                y[(size_t)grow * DIM_O + col] =
                    __builtin_fmaf((float)acc[rt][ct][qi], sf, bv);
            }
        }
    }
#undef READA
#undef LOADB2
#undef STAGE2
#undef SOFT_BARRIER
}

extern "C" void kernel_launch(void* const* d_in, const int* in_sizes, int n_in,
                              void* d_out, int out_size, void* d_ws, size_t ws_size,
                              hipStream_t stream) {
    const float* x      = (const float*)d_in[0];
    const float* coeffs = (const float*)d_in[1];
    const float* bias   = (const float*)d_in[2];
    float* y = (float*)d_out;
    float*        scales = (float*)d_ws;                      // 1 KB
    unsigned int* wp     = (unsigned int*)((char*)d_ws + 1024); // 512 KB

    const int n_tokens = in_sizes[0] / DIM_D;     // 65536

    pack_w_kernel<<<DIM_O, 256, 0, stream>>>(coeffs, wp, scales);
    cfkan_kernel<<<n_tokens / BM, 256, 0, stream>>>(
        x, (const i32x4*)wp, scales, bias, y);
}